// Round 8
// baseline (145.575 us; speedup 1.0000x reference)
//
#include <hip/hip_runtime.h>
#include <cstdint>

#define B2 2
#define CCH 256
#define HH 64
#define WW 64
#define HWHW 4096
#define KOUT 324

typedef _Float16 half_t;
typedef _Float16 h2 __attribute__((ext_vector_type(2)));
typedef _Float16 h8 __attribute__((ext_vector_type(8)));
typedef float f32x4 __attribute__((ext_vector_type(4)));

// padded level-0 (96x96, origin 16,16) and level-1 (64x64, origin 16,16)
#define P0 96
#define P1 64

__device__ __forceinline__ float fdot2f(h2 a, h2 b, float c) {
#if __has_builtin(__builtin_amdgcn_fdot2)
  return __builtin_amdgcn_fdot2(a, b, c, false);
#else
  return c + (float)a.x * (float)b.x + (float)a.y * (float)b.y;
#endif
}

// ---------------------------------------------------------------------------
// z<2: fmap1 -> f1t (B,HW,C) f16 scaled 1/16.  z=2,3: fmap2 -> f2l0p interior.
// z=4: zero the PAD regions of f2l0p and f2l1p (disjoint from all interiors,
// so it can share the kernel). grid (128, 8, 5), block (32,8).
// ---------------------------------------------------------------------------
__global__ __launch_bounds__(256) void transpose_cl(
    const float* __restrict__ f1, const float* __restrict__ f2,
    half_t* __restrict__ f1t, half_t* __restrict__ f2l0p,
    half_t* __restrict__ f2l1p) {
  int zz = blockIdx.z;
  if (zz == 4) {
    // 1024 blocks: 640 for l0p pads (5120 px), 384 for l1p pads (3072 px).
    // Each block zeroes 16 px (16 x 512B = 8 KB = 512 float4, 2/thread).
    const float4 zero = make_float4(0.f, 0.f, 0.f, 0.f);
    int pb = blockIdx.y * 128 + blockIdx.x;
    int t = threadIdx.y * 32 + threadIdx.x;
#pragma unroll
    for (int rep = 0; rep < 2; rep++) {
      int f4 = t + rep * 256;
      int pxi = f4 >> 5;
      int c = f4 & 31;
      if (pb < 640) {
        int b = pb / 320, r = pb - b * 320;
        int e = r * 16 + pxi;          // 0..5119 pad px of 96x96, interior [16,80)
        int y, x;
        if (e < 1536)      { y = e / 96; x = e - y * 96; }
        else if (e < 3072) { int e2 = e - 1536; int yy = e2 / 96; y = 80 + yy; x = e2 - yy * 96; }
        else if (e < 4096) { int e2 = e - 3072; y = 16 + (e2 >> 4); x = e2 & 15; }
        else               { int e2 = e - 4096; y = 16 + (e2 >> 4); x = 80 + (e2 & 15); }
        ((float4*)f2l0p)[((size_t)b * P0 * P0 + y * P0 + x) * 32 + c] = zero;
      } else {
        int pb2 = pb - 640;
        int b = pb2 / 192, r = pb2 - b * 192;
        int e = r * 16 + pxi;          // 0..3071 pad px of 64x64, interior [16,48)
        int y, x;
        if (e < 1024)      { y = e >> 6; x = e & 63; }
        else if (e < 2048) { int e2 = e - 1024; y = 48 + (e2 >> 6); x = e2 & 63; }
        else if (e < 2560) { int e2 = e - 2048; y = 16 + (e2 >> 4); x = e2 & 15; }
        else               { int e2 = e - 2560; y = 16 + (e2 >> 4); x = 48 + (e2 & 15); }
        ((float4*)f2l1p)[((size_t)b * P1 * P1 + y * P1 + x) * 32 + c] = zero;
      }
    }
    return;
  }

  __shared__ float tile[32][33];
  const float* src = (zz < 2) ? f1 : f2;
  float s = (zz < 2) ? 0.0625f : 1.0f;
  int b = zz & 1;
  int hw0 = blockIdx.x * 32;
  int c0 = blockIdx.y * 32;
  int tx = threadIdx.x;
  int ty = threadIdx.y;
  const float* sb = src + (size_t)b * CCH * HWHW;
#pragma unroll
  for (int i = 0; i < 4; i++)
    tile[ty + i * 8][tx] = sb[(size_t)(c0 + ty + i * 8) * HWHW + hw0 + tx];
  __syncthreads();
  if (zz < 2) {
    half_t* db = f1t + (size_t)b * HWHW * CCH;
#pragma unroll
    for (int i = 0; i < 4; i++)
      db[(size_t)(hw0 + ty + i * 8) * CCH + c0 + tx] = (half_t)(tile[tx][ty + i * 8] * s);
  } else {
    half_t* db = f2l0p + (size_t)b * P0 * P0 * CCH;
#pragma unroll
    for (int i = 0; i < 4; i++) {
      int hw = hw0 + ty + i * 8;
      int y = hw >> 6, x = hw & 63;
      db[(size_t)((y + 16) * P0 + (x + 16)) * CCH + c0 + tx] = (half_t)tile[tx][ty + i * 8];
    }
  }
}

// ---------------------------------------------------------------------------
// Pyramid levels 1..3 from padded level 0. l1 written padded (interior),
// l2 (16x16), l3 (8x8) unpadded. f16 in/out, fp32 accum.
// ---------------------------------------------------------------------------
__global__ __launch_bounds__(256) void pool_all(
    const h2* __restrict__ l0p, h2* __restrict__ l1p,
    h2* __restrict__ l2, h2* __restrict__ l3) {
  int idx = blockIdx.x * blockDim.x + threadIdx.x;
  const int n1 = B2 * 32 * 32 * 128;
  const int n2 = B2 * 16 * 16 * 128;
  const int n3 = B2 * 8 * 8 * 128;
  int L, Wo, local;
  if (idx < n1) { L = 1; Wo = 32; local = idx; }
  else if (idx < n1 + n2) { L = 2; Wo = 16; local = idx - n1; }
  else if (idx < n1 + n2 + n3) { L = 3; Wo = 8; local = idx - n1 - n2; }
  else return;
  int f = 1 << L;
  int sh = 6 - L;
  int c2 = local & 127;
  int t = local >> 7;
  int x = t & (Wo - 1);
  int y = (t >> sh) & (Wo - 1);
  int b = t >> (2 * sh);
  const h2* src = l0p + (size_t)b * P0 * P0 * 128 + c2;
  float ax = 0.f, ay = 0.f;
  for (int dy = 0; dy < f; dy++)
    for (int dx = 0; dx < f; dx++) {
      h2 a = src[(size_t)((y * f + dy + 16) * P0 + (x * f + dx + 16)) * 128];
      ax += (float)a.x; ay += (float)a.y;
    }
  float s = 1.0f / (float)(f * f);
  h2 r;
  r.x = (half_t)(ax * s);
  r.y = (half_t)(ay * s);
  if (L == 1)
    l1p[((size_t)b * P1 * P1 + (size_t)(y + 16) * P1 + (x + 16)) * 128 + c2] = r;
  else if (L == 2)
    l2[local] = r;
  else
    l3[local] = r;
}

// ---------------------------------------------------------------------------
// corr23: full level-2 (16x16) + level-3 (8x8) correlation fields via MFMA.
// Block = 16 queries, 4 waves; wave w does tap-tiles w*5..w*5+4.
// ---------------------------------------------------------------------------
__global__ __launch_bounds__(256) void corr23_k(
    const half_t* __restrict__ f1t,
    const half_t* __restrict__ f2l2, const half_t* __restrict__ f2l3,
    float* __restrict__ corr) {
  int bid = blockIdx.x;
  int g = ((bid & 7) << 6) | (bid >> 3);   // XCD swizzle (512 blocks)
  int n0 = g << 4;
  int b = n0 >> 12;
  int w = threadIdx.x >> 6;
  int l = threadIdx.x & 63;
  int row = l & 15;
  int kg = l >> 4;

  const h8* A = (const h8*)(f1t + ((size_t)(n0 + row) * CCH) + kg * 8);
  h8 a[8];
#pragma unroll
  for (int ks = 0; ks < 8; ks++) a[ks] = A[ks * 4];

  for (int nt = w * 5; nt < w * 5 + 5; nt++) {
    const half_t* Bb = (nt < 16)
        ? f2l2 + ((size_t)b * 256 + nt * 16) * CCH
        : f2l3 + ((size_t)b * 64 + (nt - 16) * 16) * CCH;
    const h8* Bp = (const h8*)(Bb + (size_t)row * CCH + kg * 8);
    f32x4 acc = {0.f, 0.f, 0.f, 0.f};
#pragma unroll
    for (int ks = 0; ks < 8; ks++)
      acc = __builtin_amdgcn_mfma_f32_16x16x32_f16(a[ks], Bp[ks * 4], acc, 0, 0, 0);
#pragma unroll
    for (int r = 0; r < 4; r++) {
      int q = kg * 4 + r;
      corr[(size_t)(n0 + q) * 320 + nt * 16 + row] = acc[r];
    }
  }
}

// ---------------------------------------------------------------------------
// 16-lane sum via DPP: quad xor1, quad xor2, row_half_mirror, row_mirror.
// ---------------------------------------------------------------------------
__device__ __forceinline__ float dpp_sum16(float x) {
  int v;
  v = __builtin_amdgcn_update_dpp(0, __float_as_int(x), 0xB1, 0xF, 0xF, true);
  x += __int_as_float(v);
  v = __builtin_amdgcn_update_dpp(0, __float_as_int(x), 0x4E, 0xF, 0xF, true);
  x += __int_as_float(v);
  v = __builtin_amdgcn_update_dpp(0, __float_as_int(x), 0x141, 0xF, 0xF, true);
  x += __int_as_float(v);
  v = __builtin_amdgcn_update_dpp(0, __float_as_int(x), 0x140, 0xF, 0xF, true);
  x += __int_as_float(v);
  return x;
}

// ---------------------------------------------------------------------------
// sample8: block = 8 consecutive queries, 8 waves. Wave w: level l = w>>2
// (0/1), pair p = w&3 -> queries {2p, 2p+1} SEQUENTIAL (register-lean; MLP
// comes from 32 waves/CU at 4 blocks/CU). Padded images -> no bounds checks.
// Levels 2/3 from corr field gathers. Direct (B,324,H,W) output.
// ---------------------------------------------------------------------------
__global__ __launch_bounds__(512, 8) void sample8(
    const float* __restrict__ coords,
    const half_t* __restrict__ f1t,
    const half_t* __restrict__ f2l0p, const half_t* __restrict__ f2l1p,
    const float* __restrict__ corr,
    float* __restrict__ out) {
  __shared__ float4 f1s4[256];     // 4 KB: 8 q x 256 ch f16 (pre-scaled)
  __shared__ float P[2][8][100];   // 6.4 KB
  __shared__ float wgt[2][8][4];
  __shared__ float cxy[2][8];

  int bid = blockIdx.x;
  int g = ((bid & 7) << 7) | (bid >> 3);   // XCD-contiguous (1024 blocks)
  int n0 = g << 3;
  int b = n0 >> 12;
  int i0 = n0 & 4095;
  int yi = i0 >> 6;
  int x0 = i0 & 63;
  int tid = threadIdx.x;

  if (tid < 256) f1s4[tid] = ((const float4*)(f1t + (size_t)n0 * CCH))[tid];
  if (tid < 16) {
    int q = tid & 7, c = tid >> 3;
    cxy[c][q] = coords[(size_t)(b * 2 + c) * HWHW + i0 + q];
  }
  __syncthreads();

  int w = tid >> 6;
  int l = w >> 2;          // level 0 or 1
  int p = w & 3;           // query pair
  int lane = tid & 63;
  int lg = lane >> 4;
  int l16 = lane & 15;

  int Pl = (l == 0) ? P0 : P1;
  float inv = (l == 0) ? 1.0f : 0.5f;
  const float4* f2b = (l == 0)
      ? (const float4*)f2l0p + ((size_t)b * P0 * P0 + 16 * P0 + 16) * 32 + l16
      : (const float4*)f2l1p + ((size_t)b * P1 * P1 + 16 * P1 + 16) * 32 + l16;
  const h2* f1h = (const h2*)f1s4;
  const int dP = 4 * Pl;
  const int dW = 1 - 10 * Pl;

  for (int qq = 0; qq < 2; qq++) {
    int q = 2 * p + qq;
    float xl = cxy[0][q] * inv, yl = cxy[1][q] * inv;
    float fx = floorf(xl), fy = floorf(yl);
    int ix0 = (int)fx - 4, iy0 = (int)fy - 4;
    if (lane == 0) {
      wgt[l][q][0] = 1.0f - (xl - fx); wgt[l][q][1] = xl - fx;
      wgt[l][q][2] = 1.0f - (yl - fy); wgt[l][q][3] = yl - fy;
    }
    int fi = q * 128 + l16 * 4;
    h2 a0 = f1h[fi + 0], a1 = f1h[fi + 1], a2 = f1h[fi + 2], a3 = f1h[fi + 3];
    h2 a4 = f1h[fi + 64], a5 = f1h[fi + 65], a6 = f1h[fi + 66], a7 = f1h[fi + 67];

    int v = lg, t = lg;
    int off = (iy0 + lg) * Pl + ix0;
    for (int it = 0; it < 25; it++) {
      const float4* tp = f2b + (ptrdiff_t)off * 32;
      float4 A = tp[0];
      float4 Bv = tp[16];
      const h2* ah = (const h2*)&A;
      const h2* bh = (const h2*)&Bv;
      float d = 0.f;
      d = fdot2f(ah[0], a0, d); d = fdot2f(ah[1], a1, d);
      d = fdot2f(ah[2], a2, d); d = fdot2f(ah[3], a3, d);
      d = fdot2f(bh[0], a4, d); d = fdot2f(bh[1], a5, d);
      d = fdot2f(bh[2], a6, d); d = fdot2f(bh[3], a7, d);
      d = dpp_sum16(d);
      if (l16 == 0) P[l][q][t] = d;
      t += 4; v += 4;
      off += dP;
      if (v >= 10) { v -= 10; off += dW; }
    }
  }
  __syncthreads();

  // ---- epilogue A: levels 0,1 from P ----
#pragma unroll
  for (int it = 0; it < 3; it++) {
    int kidx = it * 64 + (tid >> 3);
    if (kidx < 162) {
      int lvl = kidx >= 81;
      int k = kidx - 81 * lvl;
      int q = tid & 7;
      int a = k / 9, bb2 = k - a * 9;
      float wx0 = wgt[lvl][q][0], wx1 = wgt[lvl][q][1];
      float wy0 = wgt[lvl][q][2], wy1 = wgt[lvl][q][3];
      const float* Pq = P[lvl][q];
      float val = wy0 * (wx0 * Pq[a * 10 + bb2] + wx1 * Pq[(a + 1) * 10 + bb2])
                + wy1 * (wx0 * Pq[a * 10 + bb2 + 1] + wx1 * Pq[(a + 1) * 10 + bb2 + 1]);
      out[(size_t)(b * KOUT + lvl * 81 + k) * HWHW + (size_t)yi * WW + x0 + q] = val;
    }
  }

  // ---- epilogue B: levels 2,3 via 4-point gathers from corr field ----
#pragma unroll
  for (int it = 0; it < 3; it++) {
    int kidx = it * 64 + (tid >> 3);
    if (kidx < 162) {
      int lvl = 2 + (kidx >= 81);
      int k = kidx - 81 * (kidx >= 81);
      int q = tid & 7;
      float inv2 = (lvl == 2) ? 0.25f : 0.125f;
      int Wl2 = (lvl == 2) ? 16 : 8;
      int base = (lvl == 2) ? 0 : 256;
      float xl = cxy[0][q] * inv2, yl = cxy[1][q] * inv2;
      float fx = floorf(xl), fy = floorf(yl);
      int ix0 = (int)fx - 4, iy0 = (int)fy - 4;
      float wx1 = xl - fx, wx0 = 1.0f - wx1;
      float wy1 = yl - fy, wy0 = 1.0f - wy1;
      const float* cq = corr + (size_t)(n0 + q) * 320 + base;
      int a = k / 9, bb2 = k - a * 9;
      float p00 = 0.f, p10 = 0.f, p01 = 0.f, p11 = 0.f;
      {
        int x = ix0 + a, y = iy0 + bb2;
        if (((unsigned)x < (unsigned)Wl2) & ((unsigned)y < (unsigned)Wl2)) p00 = cq[y * Wl2 + x];
      }
      {
        int x = ix0 + a + 1, y = iy0 + bb2;
        if (((unsigned)x < (unsigned)Wl2) & ((unsigned)y < (unsigned)Wl2)) p10 = cq[y * Wl2 + x];
      }
      {
        int x = ix0 + a, y = iy0 + bb2 + 1;
        if (((unsigned)x < (unsigned)Wl2) & ((unsigned)y < (unsigned)Wl2)) p01 = cq[y * Wl2 + x];
      }
      {
        int x = ix0 + a + 1, y = iy0 + bb2 + 1;
        if (((unsigned)x < (unsigned)Wl2) & ((unsigned)y < (unsigned)Wl2)) p11 = cq[y * Wl2 + x];
      }
      float val = wy0 * (wx0 * p00 + wx1 * p10) + wy1 * (wx0 * p01 + wx1 * p11);
      out[(size_t)(b * KOUT + lvl * 81 + k) * HWHW + (size_t)yi * WW + x0 + q] = val;
    }
  }
}

// ---------------------------------------------------------------------------
extern "C" void kernel_launch(void* const* d_in, const int* in_sizes, int n_in,
                              void* d_out, int out_size, void* d_ws, size_t ws_size,
                              hipStream_t stream) {
  const float* fmap1 = (const float*)d_in[0];
  const float* fmap2 = (const float*)d_in[1];
  const float* coords = (const float*)d_in[2];
  float* out = (float*)d_out;

  char* ws = (char*)d_ws;
  half_t* f1t   = (half_t*)(ws);                   // 4 MB  @ 0
  half_t* f2l0p = (half_t*)(ws + 4194304);         // 9.44 MB (B,96,96,C) padded
  half_t* f2l1p = (half_t*)(ws + 13631488);        // 4.19 MB (B,64,64,C) padded
  half_t* f2l2  = (half_t*)(ws + 17825792);        // 256 KB (B,16,16,C)
  half_t* f2l3  = (half_t*)(ws + 18087936);        // 64 KB  (B,8,8,C)
  float*  corr  = (float*)(ws + 18153472);         // 10.5 MB (B*HW, 320) fp32

  dim3 tb(32, 8, 1);
  dim3 tg(HWHW / 32, CCH / 32, 5);   // z=4 zeroes l0p/l1p pads
  transpose_cl<<<tg, tb, 0, stream>>>(fmap1, fmap2, f1t, f2l0p, f2l1p);

  int npool = B2 * (32 * 32 + 16 * 16 + 8 * 8) * 128;
  pool_all<<<(npool + 255) / 256, 256, 0, stream>>>(
      (const h2*)f2l0p, (h2*)f2l1p, (h2*)f2l2, (h2*)f2l3);

  corr23_k<<<512, 256, 0, stream>>>(f1t, f2l2, f2l3, corr);

  sample8<<<1024, 512, 0, stream>>>(coords, f1t, f2l0p, f2l1p, corr, out);
}